// Round 4
// baseline (544.794 us; speedup 1.0000x reference)
//
#include <hip/hip_runtime.h>

// 4D conv net, MI355X. S=30, B=2, ch 1->10->10->1, kernel 3^4, pad 1, ReLU.
// out = net(x,w) + net(x,w_swap), w_swap has (k1,k2)<->(k3,k4).
// R7: all layers as 32x32x16 bf16 MFMA, M = 32 padded t-positions, K = 16
// channels, N = k4*10+co. Cross-k4 combine in epilogue via per-wave LDS.
// R8: XCD-chunk swizzle (FETCH 273->52 MB), full-line stores, barrier-free.
// R9/R10: depth-1 A/B prefetch pipeline + s-outer/r-inner MFMA order.
// R11: the kernel is TA/L1 line-throughput bound (~144 lines per wave-tap,
// MfmaUtil pinned at 22% across 3 occupancy/pipeline changes). Cut lines:
//   (1) B-frag table (27.6 KB, block-invariant) staged to LDS once per
//       block; tap-loop B reads via ds_read_b128 (DS pipe, off TA path).
//   (2) Packed planes: row = 32x16B (ch0-7) + 32x4B (ch8-9) = 640 B
//       (was 1024 B with ch10-15 = stored zeros). hl=0 lanes load uint4,
//       hl=1 lanes load u32 + zero-fill upper channels in-register.
//   => ~60 lines per wave-tap (2.4x less TA demand). LDS 44.5 KB, 3 blk/CU.

static constexpr int S  = 30;
static constexpr long S4 = 810000;
static constexpr size_t ROWB  = 640;                    // 32*16 + 32*4 B
static constexpr size_t PLANE = 32 * ROWB;              // 20480 B
static constexpr size_t YBYTES = (size_t)1800 * PLANE;  // [b(2)][g1][g2]

typedef __bf16 bf16x8 __attribute__((ext_vector_type(8)));
typedef float  f32x16 __attribute__((ext_vector_type(16)));
typedef unsigned int  u32;
typedef unsigned short u16;

static __device__ __forceinline__ u16 f2bf(float f) {
    u32 u = __builtin_bit_cast(u32, f);
    return (u16)((u + 0x7fffu + ((u >> 16) & 1u)) >> 16);
}

// ---------------------------------------------------------------------------
// B-fragment table: [set(6)][k12(9)][k3(3)][lane(64)] uint4.
// set = layer*2 + branch. Layer 0: w1 (K slot 0 only); 1: w2 (K = c, 10/16);
// 2: w3 (K = c, cols {0,10,20} only). N: n = k4*10 + co (n<30).
// B[k][n]: lane = n + 32*hl holds k = hl*8 + j.
__global__ __launch_bounds__(256) void fragprep_k(u32* __restrict__ ft,
    const float* __restrict__ w1, const float* __restrict__ w2,
    const float* __restrict__ w3)
{
    const int gid = blockIdx.x * 256 + threadIdx.x;
    if (gid >= 6 * 27 * 64) return;
    const int lane = gid & 63;
    int r = gid >> 6;
    const int k3 = r % 3; r /= 3;
    const int k12 = r % 9; const int set = r / 9;
    const int layer = set >> 1, swap = set & 1;
    const int k1 = k12 / 3, k2 = k12 % 3;
    const int n = lane & 31, hl = lane >> 5;

    u16 us[8];
#pragma unroll
    for (int j = 0; j < 8; ++j) us[j] = 0;
    if (n < 30) {
        const int k4 = (n < 10) ? 0 : ((n < 20) ? 1 : 2);
        const int co = n - 10 * k4;
        const int i1 = swap ? k3 : k1, i2 = swap ? k4 : k2;
        const int i3 = swap ? k1 : k3, i4 = swap ? k2 : k4;
        const int widx = ((i1 * 3 + i2) * 3 + i3) * 3 + i4;
#pragma unroll
        for (int j = 0; j < 8; ++j) {
            const int k = hl * 8 + j;
            float wv = 0.f;
            if (layer == 0) { if (k == 0) wv = w1[co * 81 + widx]; }
            else if (layer == 1) { if (k < 10) wv = w2[(co * 10 + k) * 81 + widx]; }
            else { if (k < 10 && co == 0) wv = w3[k * 81 + widx]; }
            us[j] = f2bf(wv);
        }
    }
    u32* o = ft + (size_t)gid * 4;
    o[0] = (u32)us[0] | ((u32)us[1] << 16);
    o[1] = (u32)us[2] | ((u32)us[3] << 16);
    o[2] = (u32)us[4] | ((u32)us[5] << 16);
    o[3] = (u32)us[6] | ((u32)us[7] << 16);
}

// ---------------------------------------------------------------------------
// Zero halo positions of all 1800 packed planes of y1 and y2.
// Plane: 32 rows x 640 B; row: [pos(32)]x16B ch0-7 then [pos(32)]x4B ch8-9.
// Halos: full rows h' in {0,31}; in rows 1..30, pos 0 and 31.
__global__ __launch_bounds__(128) void zerok(u16* __restrict__ y1, u16* __restrict__ y2)
{
    const int pb = blockIdx.x, tid = threadIdx.x;
    char* p1 = (char*)y1 + (size_t)pb * PLANE;
    char* p2 = (char*)y2 + (size_t)pb * PLANE;
    const uint4 z4 = make_uint4(0, 0, 0, 0);
    if (tid < 80) {
        const int rowi = tid / 40, i = tid % 40;      // rows 0 and 31, 40 uint4
        const size_t off = (size_t)(rowi ? 31 : 0) * ROWB + (size_t)i * 16;
        *(uint4*)(p1 + off) = z4; *(uint4*)(p2 + off) = z4;
    } else if (tid < 110) {
        const int h = tid - 79;                        // 1..30
        const size_t rb = (size_t)h * ROWB;
        *(uint4*)(p1 + rb)       = z4; *(uint4*)(p2 + rb)       = z4;  // pos0 ch0-7
        *(uint4*)(p1 + rb + 496) = z4; *(uint4*)(p2 + rb + 496) = z4;  // pos31 ch0-7
        *(u32*)(p1 + rb + 512) = 0u;   *(u32*)(p2 + rb + 512) = 0u;    // pos0 ch8-9
        *(u32*)(p1 + rb + 636) = 0u;   *(u32*)(p2 + rb + 636) = 0u;    // pos31 ch8-9
    }
}

// ---------------------------------------------------------------------------
// Unified conv layer. Work item = (w1, h1, z) with z = b*2 + half; block
// computes h2 rows [half*15, half*15+15). Wave wv owns 4 rows (wave 3: 3).
// XCD-chunk swizzle: wgid%8 = hardware XCD, contiguous 450-id strips.
// B-frag table staged to LDS at block start (one barrier); tap loop reads
// B via ds_read. Depth-1 pipeline on A (global) + B (LDS).
// LAYER 0: in = x fp32 (bf16-cast at consume, K slot 0).
// LAYER 1: in = y1 packed planes, out = y2 packed planes.
// LAYER 2: in = y2, out = fp32 d_out (ACCUM adds for branch 1).
template<int LAYER, bool ACCUM>
__global__ __launch_bounds__(256, 3) void conv_k(
    const void* __restrict__ inp, const u32* __restrict__ ftab,
    const float* __restrict__ bias, void* __restrict__ outp)
{
    __shared__ float E[4][1056];          // per-wave 32 cols x 33-stride rows
    __shared__ uint4 BT[1728];            // [k12(9)][k3(3)][lane(64)]

    const int tid = threadIdx.x;
    // ---- stage B table to LDS (27.6 KB, once per block) ----
    {
        const uint4* g = (const uint4*)ftab;
#pragma unroll
        for (int j = 0; j < 7; ++j) {
            const int idx = j * 256 + tid;
            if (idx < 1728) BT[idx] = g[idx];
        }
    }
    __syncthreads();

    // --- XCD-chunk work swizzle (bijective, 3600 % 8 == 0) ---
    const int wgid = blockIdx.x + S * blockIdx.y + 900 * blockIdx.z;
    const int id2  = (wgid & 7) * 450 + (wgid >> 3);
    const int half = id2 & 1;
    int sp = id2 >> 1;                    // b*900 + h1*30 + w1
    const int w1i = sp % S; sp /= S;
    const int h1  = sp % S;
    const int b   = sp / S;

    const int lane = tid & 63, wv = tid >> 6;
    const int m = lane & 31, hl = lane >> 5;    // A: row m = padded t', k-grp hl
    const int rbase = half * 15 + wv * 4;
    const int rcnt = (wv == 3) ? 3 : 4;
    const int off0 = hl ? (512 + m * 4) : (m * 16);   // byte off within row

    int kl[9], nk = 0;
    for (int k12 = 0; k12 < 9; ++k12) {
        const int g1 = h1 + k12 / 3 - 1, g2 = w1i + k12 % 3 - 1;
        if (g1 >= 0 && g1 < S && g2 >= 0 && g2 < S)
            kl[nk++] = (g1 * S + g2) | (k12 << 10);
    }

    f32x16 acc[4];
#pragma unroll
    for (int r = 0; r < 4; ++r)
#pragma unroll
        for (int e = 0; e < 16; ++e) acc[r][e] = 0.f;

    // ---- B frags (LDS) + A loads for tap 0 ----
    uint4 B0[3];
    {
        const int k0 = kl[0] >> 10;
#pragma unroll
        for (int f = 0; f < 3; ++f) B0[f] = BT[(k0 * 3 + f) * 64 + lane];
    }
    uint4 F[6];                           // layers 1,2 A state
    float fx[6];                          // layer 0 A state
    {
        const int g = kl[0] & 1023;
        if (LAYER == 0) {
            const float* xp = (const float*)inp + ((size_t)b * 900 + g) * 900;
#pragma unroll
            for (int f = 0; f < 6; ++f) {
                if (f > rcnt + 1) continue;
                const int hp = rbase + f;
                float v = 0.f;
                if (hl == 0 && hp >= 1 && hp <= 30 && m >= 1 && m <= 30)
                    v = xp[(hp - 1) * 30 + (m - 1)];
                fx[f] = v;
            }
        } else {
            const char* P = (const char*)inp + ((size_t)b * 900 + g) * PLANE
                            + (size_t)rbase * ROWB + off0;
#pragma unroll
            for (int f = 0; f < 6; ++f) {
                if (f > rcnt + 1) continue;
                if (hl == 0) F[f] = *(const uint4*)(P + f * ROWB);
                else         F[f] = make_uint4(*(const u32*)(P + f * ROWB), 0u, 0u, 0u);
            }
        }
    }

    // ---- pipelined tap loop: prefetch ki+1, compute ki ----
    for (int ki = 0; ki + 1 < nk; ++ki) {
        const int gn = kl[ki + 1] & 1023, kn = kl[ki + 1] >> 10;
        uint4 FN[6]; float fn[6];
        if (LAYER == 0) {
            const float* xp = (const float*)inp + ((size_t)b * 900 + gn) * 900;
#pragma unroll
            for (int f = 0; f < 6; ++f) {
                if (f > rcnt + 1) continue;
                const int hp = rbase + f;
                float v = 0.f;
                if (hl == 0 && hp >= 1 && hp <= 30 && m >= 1 && m <= 30)
                    v = xp[(hp - 1) * 30 + (m - 1)];
                fn[f] = v;
            }
        } else {
            const char* P = (const char*)inp + ((size_t)b * 900 + gn) * PLANE
                            + (size_t)rbase * ROWB + off0;
#pragma unroll
            for (int f = 0; f < 6; ++f) {
                if (f > rcnt + 1) continue;
                if (hl == 0) FN[f] = *(const uint4*)(P + f * ROWB);
                else         FN[f] = make_uint4(*(const u32*)(P + f * ROWB), 0u, 0u, 0u);
            }
        }
        uint4 BN[3];
#pragma unroll
        for (int f = 0; f < 3; ++f) BN[f] = BT[(kn * 3 + f) * 64 + lane];

        uint4 FA[6];
#pragma unroll
        for (int f = 0; f < 6; ++f) {
            if (f > rcnt + 1) continue;
            if (LAYER == 0) FA[f] = make_uint4((u32)f2bf(fx[f]), 0u, 0u, 0u);
            else            FA[f] = F[f];
        }
        // s-outer / r-inner: 4 independent MFMAs between dependent pairs
#pragma unroll
        for (int ss = 0; ss < 3; ++ss)
#pragma unroll
            for (int r = 0; r < 4; ++r) {
                if (r >= rcnt) continue;              // wave-uniform
                acc[r] = __builtin_amdgcn_mfma_f32_32x32x16_bf16(
                    __builtin_bit_cast(bf16x8, FA[r + ss]),
                    __builtin_bit_cast(bf16x8, B0[ss]), acc[r], 0, 0, 0);
            }
#pragma unroll
        for (int f = 0; f < 6; ++f) {
            if (f > rcnt + 1) continue;
            if (LAYER == 0) fx[f] = fn[f]; else F[f] = FN[f];
        }
#pragma unroll
        for (int f = 0; f < 3; ++f) B0[f] = BN[f];
    }
    // ---- peeled last tap ----
    {
        uint4 FA[6];
#pragma unroll
        for (int f = 0; f < 6; ++f) {
            if (f > rcnt + 1) continue;
            if (LAYER == 0) FA[f] = make_uint4((u32)f2bf(fx[f]), 0u, 0u, 0u);
            else            FA[f] = F[f];
        }
#pragma unroll
        for (int ss = 0; ss < 3; ++ss)
#pragma unroll
            for (int r = 0; r < 4; ++r) {
                if (r >= rcnt) continue;
                acc[r] = __builtin_amdgcn_mfma_f32_32x32x16_bf16(
                    __builtin_bit_cast(bf16x8, FA[r + ss]),
                    __builtin_bit_cast(bf16x8, B0[ss]), acc[r], 0, 0, 0);
            }
    }

    // ---- epilogue: per-wave LDS transpose, combine k4 shifts ----
    // out[t][co] = sum_k4 P[t+k4][k4*10+co]. C/D: col(n)=lane&31,
    // row(t') = (reg&3) + 8*(reg>>2) + 4*hl. E is per-wave: barrier-free.
    float* Ew = E[wv];
    for (int r = 0; r < 4; ++r) {
        if (r >= rcnt) continue;                     // wave-uniform
#pragma unroll
        for (int gq = 0; gq < 4; ++gq)
#pragma unroll
            for (int r4 = 0; r4 < 4; ++r4)
                Ew[m * 33 + 4 * hl + 8 * gq + r4] = acc[r][gq * 4 + r4];

        const int h2 = rbase + r;
        if (LAYER <= 1) {
            char* pl = (char*)outp + ((size_t)b * 900 + h1 * S + w1i) * PLANE
                       + (size_t)(h2 + 1) * ROWB;
            if (lane < 30) {                          // ch0-7 of t = lane
                const int t = lane;
                u32 wo[4];
#pragma unroll
                for (int p = 0; p < 4; ++p) {
                    const int c0 = 2 * p, c1 = 2 * p + 1;
                    float v0 = fmaxf(Ew[c0 * 33 + t] + Ew[(10 + c0) * 33 + t + 1]
                                   + Ew[(20 + c0) * 33 + t + 2] + bias[c0], 0.f);
                    float v1 = fmaxf(Ew[c1 * 33 + t] + Ew[(10 + c1) * 33 + t + 1]
                                   + Ew[(20 + c1) * 33 + t + 2] + bias[c1], 0.f);
                    wo[p] = (u32)f2bf(v0) | ((u32)f2bf(v1) << 16);
                }
                *(uint4*)(pl + (t + 1) * 16) =
                    make_uint4(wo[0], wo[1], wo[2], wo[3]);
            } else if (lane >= 32 && lane < 62) {     // ch8-9 of t = lane-32
                const int t = lane - 32;
                float v8 = fmaxf(Ew[8 * 33 + t] + Ew[18 * 33 + t + 1]
                               + Ew[28 * 33 + t + 2] + bias[8], 0.f);
                float v9 = fmaxf(Ew[9 * 33 + t] + Ew[19 * 33 + t + 1]
                               + Ew[29 * 33 + t + 2] + bias[9], 0.f);
                *(u32*)(pl + 512 + (t + 1) * 4) =
                    (u32)f2bf(v8) | ((u32)f2bf(v9) << 16);
            }
        } else {
            if (lane < 30) {
                const int t = lane;
                float v = Ew[t] + Ew[330 + t + 1] + Ew[660 + t + 2] + bias[0];
                v = fmaxf(v, 0.f);
                float* o = (float*)outp + (size_t)b * S4
                           + (size_t)(h1 * S + w1i) * 900 + h2 * 30 + t;
                if (ACCUM) *o += v; else *o = v;
            }
        }
    }
}

// ---------------------------------------------------------------------------
extern "C" void kernel_launch(void* const* d_in, const int* in_sizes, int n_in,
                              void* d_out, int out_size, void* d_ws, size_t ws_size,
                              hipStream_t stream)
{
    const float* x   = (const float*)d_in[0];
    const float* w1p = (const float*)d_in[1];
    const float* b1p = (const float*)d_in[2];
    const float* w2p = (const float*)d_in[3];
    const float* b2p = (const float*)d_in[4];
    const float* w3p = (const float*)d_in[5];
    const float* b3p = (const float*)d_in[6];
    float* out = (float*)d_out;

    // ws: fragtab 6*27*64 uint4 = 165888 B | y1 36.9 MB | y2 36.9 MB
    u32* ft = (u32*)d_ws;
    u16* y1 = (u16*)((char*)d_ws + 165888);
    u16* y2 = (u16*)((char*)y1 + YBYTES);

    fragprep_k<<<41, 256, 0, stream>>>(ft, w1p, w2p, w3p);
    zerok<<<1800, 128, 0, stream>>>(y1, y2);

    dim3 grid(S, S, 4), blk(256);
    for (int br = 0; br < 2; ++br) {
        const u32* f1 = ft + (size_t)(0 + br) * 27 * 64 * 4;
        const u32* f2 = ft + (size_t)(2 + br) * 27 * 64 * 4;
        const u32* f3 = ft + (size_t)(4 + br) * 27 * 64 * 4;
        conv_k<0, false><<<grid, blk, 0, stream>>>(x,  f1, b1p, (void*)y1);
        conv_k<1, false><<<grid, blk, 0, stream>>>(y1, f2, b2p, (void*)y2);
        if (br == 0)
            conv_k<2, false><<<grid, blk, 0, stream>>>(y2, f3, b3p, (void*)out);
        else
            conv_k<2, true><<<grid, blk, 0, stream>>>(y2, f3, b3p, (void*)out);
    }
}

// Round 5
// 404.360 us; speedup vs baseline: 1.3473x; 1.3473x over previous
//
#include <hip/hip_runtime.h>

// 4D conv net, MI355X. S=30, B=2, ch 1->10->10->1, kernel 3^4, pad 1, ReLU.
// out = net(x,w) + net(x,w_swap), w_swap has (k1,k2)<->(k3,k4).
// R7: all layers as 32x32x16 bf16 MFMA, M = 32 padded t-positions, K = 16
// channels, N = k4*10+co. Cross-k4 combine in epilogue via per-wave LDS.
// R8: XCD-chunk swizzle (FETCH 273->52 MB), full-line stores, barrier-free.
// R9/R10: depth-1 A/B prefetch + s-outer/r-inner MFMA order (source-level).
// R11 (reverted): B-in-LDS + packed planes — slower despite half the traffic;
// proved the kernel is NOT traffic-bound. True MFMA-pipe util ~5%; ~700 cy
// exposed latency per 930-cy tap at ~2 waves/SIMD.
// R12: the depth-1 prefetch never materialized — VGPR_Count=80 < the ~95+
// a real double state needs; allocator sank the loads to their uses under
// launch_bounds(,3). Fix: (a) launch_bounds(256,2) (matches measured ~2.1
// waves/SIMD residency, frees registers so the pipeline exists in asm);
// (b) uniform straight-line tap body: all waves 4 rows / 6 loads / 12 MFMAs,
// wave3 row-3 is junk (row clamped at 31, never stored) -> no per-f/per-r
// guards, no FA copies (layer0 converts at load); (c) wave-uniform store
// guards. Verify via VGPR_Count ~105-130.

static constexpr int S  = 30;
static constexpr long S4 = 810000;
static constexpr size_t PLANE = 32768;                  // 32*32*16*2 B
static constexpr size_t YBYTES = (size_t)1800 * PLANE;  // [b(2)][g1][g2]

typedef __bf16 bf16x8 __attribute__((ext_vector_type(8)));
typedef float  f32x16 __attribute__((ext_vector_type(16)));
typedef unsigned int  u32;
typedef unsigned short u16;

static __device__ __forceinline__ u16 f2bf(float f) {
    u32 u = __builtin_bit_cast(u32, f);
    return (u16)((u + 0x7fffu + ((u >> 16) & 1u)) >> 16);
}

// ---------------------------------------------------------------------------
// B-fragment table: [set(6)][k12(9)][k3(3)][lane(64)] uint4.
// set = layer*2 + branch. Layer 0: w1 (K slot 0 only); 1: w2 (K = c, 10/16);
// 2: w3 (K = c, cols {0,10,20} only). N: n = k4*10 + co (n<30).
// B[k][n]: lane = n + 32*hl holds k = hl*8 + j.
__global__ __launch_bounds__(256) void fragprep_k(u32* __restrict__ ft,
    const float* __restrict__ w1, const float* __restrict__ w2,
    const float* __restrict__ w3)
{
    const int gid = blockIdx.x * 256 + threadIdx.x;
    if (gid >= 6 * 27 * 64) return;
    const int lane = gid & 63;
    int r = gid >> 6;
    const int k3 = r % 3; r /= 3;
    const int k12 = r % 9; const int set = r / 9;
    const int layer = set >> 1, swap = set & 1;
    const int k1 = k12 / 3, k2 = k12 % 3;
    const int n = lane & 31, hl = lane >> 5;

    u16 us[8];
#pragma unroll
    for (int j = 0; j < 8; ++j) us[j] = 0;
    if (n < 30) {
        const int k4 = (n < 10) ? 0 : ((n < 20) ? 1 : 2);
        const int co = n - 10 * k4;
        const int i1 = swap ? k3 : k1, i2 = swap ? k4 : k2;
        const int i3 = swap ? k1 : k3, i4 = swap ? k2 : k4;
        const int widx = ((i1 * 3 + i2) * 3 + i3) * 3 + i4;
#pragma unroll
        for (int j = 0; j < 8; ++j) {
            const int k = hl * 8 + j;
            float wv = 0.f;
            if (layer == 0) { if (k == 0) wv = w1[co * 81 + widx]; }
            else if (layer == 1) { if (k < 10) wv = w2[(co * 10 + k) * 81 + widx]; }
            else { if (k < 10 && co == 0) wv = w3[k * 81 + widx]; }
            us[j] = f2bf(wv);
        }
    }
    u32* o = ft + (size_t)gid * 4;
    o[0] = (u32)us[0] | ((u32)us[1] << 16);
    o[1] = (u32)us[2] | ((u32)us[3] << 16);
    o[2] = (u32)us[4] | ((u32)us[5] << 16);
    o[3] = (u32)us[6] | ((u32)us[7] << 16);
}

// ---------------------------------------------------------------------------
// Zero halo positions (h' or t' in {0,31}) of all 1800 planes of y1 and y2.
__global__ __launch_bounds__(128) void zerok(u16* __restrict__ y1, u16* __restrict__ y2)
{
    const int pb = blockIdx.x, tid = threadIdx.x;
    if (tid >= 124) return;
    int hp, tp;
    if (tid < 32)      { hp = 0;        tp = tid; }
    else if (tid < 64) { hp = 31;       tp = tid - 32; }
    else if (tid < 94) { hp = tid - 63; tp = 0; }
    else               { hp = tid - 93; tp = 31; }
    const size_t off = (size_t)pb * PLANE + hp * 1024 + tp * 32;
    const uint4 z = make_uint4(0, 0, 0, 0);
    *(uint4*)((char*)y1 + off)      = z;
    *(uint4*)((char*)y1 + off + 16) = z;
    *(uint4*)((char*)y2 + off)      = z;
    *(uint4*)((char*)y2 + off + 16) = z;
}

// ---------------------------------------------------------------------------
// Unified conv layer. Work item = (w1, h1, z) with z = b*2 + half; block
// computes h2 rows [half*15, half*15+15). Wave wv owns rows rbase..rbase+3;
// wave 3's row 3 is JUNK (computed, never stored) so the tap body is fully
// uniform. XCD-chunk swizzle as before. Depth-1 A/B prefetch with registers
// to hold it (launch_bounds(256,2)).
// LAYER 0: in = x fp32 (bf16-cast at LOAD, K slot 0).
// LAYER 1: in = y1 planes, out = y2 planes.
// LAYER 2: in = y2, out = fp32 d_out (ACCUM adds for branch 1).
template<int LAYER, bool ACCUM>
__global__ __launch_bounds__(256, 2) void conv_k(
    const void* __restrict__ inp, const u32* __restrict__ ftab,
    const float* __restrict__ bias, void* __restrict__ outp)
{
    __shared__ float E[4][1056];          // per-wave 32 cols x 33-stride rows
    // --- XCD-chunk work swizzle (bijective, 3600 % 8 == 0) ---
    const int wgid = blockIdx.x + S * blockIdx.y + 900 * blockIdx.z;
    const int id2  = (wgid & 7) * 450 + (wgid >> 3);
    const int half = id2 & 1;
    int sp = id2 >> 1;                    // b*900 + h1*30 + w1
    const int w1i = sp % S; sp /= S;
    const int h1  = sp % S;
    const int b   = sp / S;

    const int tid = threadIdx.x;
    const int lane = tid & 63, wv = tid >> 6;
    const int m = lane & 31, hl = lane >> 5;    // A: row m = padded t', k-grp hl
    const int rbase = half * 15 + wv * 4;
    const uint4* ft4 = (const uint4*)ftab;

    // Per-f input-row byte offsets (clamped: wv3 f5 would be row 32).
    int rofs[6];
#pragma unroll
    for (int f = 0; f < 6; ++f) {
        int rr = rbase + f; if (rr > 31) rr = 31;
        rofs[f] = rr * 1024;
    }

    int kl[9], nk = 0;
#pragma unroll
    for (int k12 = 0; k12 < 9; ++k12) {
        const int g1 = h1 + k12 / 3 - 1, g2 = w1i + k12 % 3 - 1;
        if (g1 >= 0 && g1 < S && g2 >= 0 && g2 < S)
            kl[nk++] = (g1 * S + g2) | (k12 << 10);
    }

    f32x16 acc[4];
#pragma unroll
    for (int r = 0; r < 4; ++r)
#pragma unroll
        for (int e = 0; e < 16; ++e) acc[r][e] = 0.f;

    // A-tile loader: 6 rows -> F[0..5] (bf16x8 per lane). Layer 0 converts
    // fp32->bf16 at load so the tap body is layer-independent.
    auto loadA = [&](uint4* Fd, int g) {
        if (LAYER == 0) {
            const float* xp = (const float*)inp + ((size_t)b * 900 + g) * 900;
#pragma unroll
            for (int f = 0; f < 6; ++f) {
                const int hp = rbase + f;
                float v = 0.f;
                if (hl == 0 && hp >= 1 && hp <= 30 && m >= 1 && m <= 30)
                    v = xp[(hp - 1) * 30 + (m - 1)];
                Fd[f] = make_uint4((u32)f2bf(v), 0u, 0u, 0u);
            }
        } else {
            const char* P = (const char*)inp + ((size_t)b * 900 + g) * PLANE
                            + m * 32 + hl * 16;
#pragma unroll
            for (int f = 0; f < 6; ++f)
                Fd[f] = *(const uint4*)(P + rofs[f]);
        }
    };

    // ---- tap 0 state ----
    uint4 B0[3];
    {
        const int k0 = kl[0] >> 10;
#pragma unroll
        for (int f = 0; f < 3; ++f) B0[f] = ft4[(k0 * 3 + f) * 64 + lane];
    }
    uint4 F[6];
    loadA(F, kl[0] & 1023);

    // ---- pipelined tap loop: prefetch ki+1, compute ki ----
    for (int ki = 0; ki + 1 < nk; ++ki) {
        const int gn = kl[ki + 1] & 1023, kn = kl[ki + 1] >> 10;
        uint4 FN[6];
        loadA(FN, gn);
        uint4 BN[3];
#pragma unroll
        for (int f = 0; f < 3; ++f) BN[f] = ft4[(kn * 3 + f) * 64 + lane];

        // s-outer / r-inner: 4 independent MFMAs between dependent pairs
#pragma unroll
        for (int ss = 0; ss < 3; ++ss)
#pragma unroll
            for (int r = 0; r < 4; ++r)
                acc[r] = __builtin_amdgcn_mfma_f32_32x32x16_bf16(
                    __builtin_bit_cast(bf16x8, F[r + ss]),
                    __builtin_bit_cast(bf16x8, B0[ss]), acc[r], 0, 0, 0);

#pragma unroll
        for (int f = 0; f < 6; ++f) F[f] = FN[f];
#pragma unroll
        for (int f = 0; f < 3; ++f) B0[f] = BN[f];
    }
    // ---- peeled last tap ----
#pragma unroll
    for (int ss = 0; ss < 3; ++ss)
#pragma unroll
        for (int r = 0; r < 4; ++r)
            acc[r] = __builtin_amdgcn_mfma_f32_32x32x16_bf16(
                __builtin_bit_cast(bf16x8, F[r + ss]),
                __builtin_bit_cast(bf16x8, B0[ss]), acc[r], 0, 0, 0);

    // ---- epilogue: per-wave LDS transpose, combine k4 shifts ----
    // out[t][co] = sum_k4 P[t+k4][k4*10+co]. C/D: col(n)=lane&31,
    // row(t') = (reg&3) + 8*(reg>>2) + 4*hl. E is per-wave: barrier-free.
    float* Ew = E[wv];
    for (int r = 0; r < 4; ++r) {
        if (wv == 3 && r == 3) continue;             // junk row, wave-uniform
#pragma unroll
        for (int gq = 0; gq < 4; ++gq)
#pragma unroll
            for (int r4 = 0; r4 < 4; ++r4)
                Ew[m * 33 + 4 * hl + 8 * gq + r4] = acc[r][gq * 4 + r4];

        const int h2 = rbase + r;
        if (LAYER <= 1) {
            char* pl = (char*)outp + ((size_t)b * 900 + h1 * S + w1i) * PLANE
                       + (size_t)(h2 + 1) * 1024;
            const int t = lane >> 1, h8 = lane & 1;
            if (t < 30) {
                u32 wo[4];
#pragma unroll
                for (int p = 0; p < 4; ++p) {
                    const int c0 = 8 * h8 + 2 * p, c1 = c0 + 1;
                    float v0 = 0.f, v1 = 0.f;
                    if (c0 < 10)
                        v0 = fmaxf(Ew[c0 * 33 + t] + Ew[(10 + c0) * 33 + t + 1]
                                 + Ew[(20 + c0) * 33 + t + 2] + bias[c0], 0.f);
                    if (c1 < 10)
                        v1 = fmaxf(Ew[c1 * 33 + t] + Ew[(10 + c1) * 33 + t + 1]
                                 + Ew[(20 + c1) * 33 + t + 2] + bias[c1], 0.f);
                    wo[p] = (u32)f2bf(v0) | ((u32)f2bf(v1) << 16);
                }
                *(uint4*)(pl + (t + 1) * 32 + h8 * 16) =
                    make_uint4(wo[0], wo[1], wo[2], wo[3]);
            }
        } else {
            if (lane < 30) {
                const int t = lane;
                float v = Ew[t] + Ew[330 + t + 1] + Ew[660 + t + 2] + bias[0];
                v = fmaxf(v, 0.f);
                float* o = (float*)outp + (size_t)b * S4
                           + (size_t)(h1 * S + w1i) * 900 + h2 * 30 + t;
                if (ACCUM) *o += v; else *o = v;
            }
        }
    }
}

// ---------------------------------------------------------------------------
extern "C" void kernel_launch(void* const* d_in, const int* in_sizes, int n_in,
                              void* d_out, int out_size, void* d_ws, size_t ws_size,
                              hipStream_t stream)
{
    const float* x   = (const float*)d_in[0];
    const float* w1p = (const float*)d_in[1];
    const float* b1p = (const float*)d_in[2];
    const float* w2p = (const float*)d_in[3];
    const float* b2p = (const float*)d_in[4];
    const float* w3p = (const float*)d_in[5];
    const float* b3p = (const float*)d_in[6];
    float* out = (float*)d_out;

    // ws: fragtab 6*27*64 uint4 = 165888 B | y1 59 MB | y2 59 MB
    u32* ft = (u32*)d_ws;
    u16* y1 = (u16*)((char*)d_ws + 165888);
    u16* y2 = (u16*)((char*)y1 + YBYTES);

    fragprep_k<<<41, 256, 0, stream>>>(ft, w1p, w2p, w3p);
    zerok<<<1800, 128, 0, stream>>>(y1, y2);

    dim3 grid(S, S, 4), blk(256);
    for (int br = 0; br < 2; ++br) {
        const u32* f1 = ft + (size_t)(0 + br) * 27 * 64 * 4;
        const u32* f2 = ft + (size_t)(2 + br) * 27 * 64 * 4;
        const u32* f3 = ft + (size_t)(4 + br) * 27 * 64 * 4;
        conv_k<0, false><<<grid, blk, 0, stream>>>(x,  f1, b1p, (void*)y1);
        conv_k<1, false><<<grid, blk, 0, stream>>>(y1, f2, b2p, (void*)y2);
        if (br == 0)
            conv_k<2, false><<<grid, blk, 0, stream>>>(y2, f3, b3p, (void*)out);
        else
            conv_k<2, true><<<grid, blk, 0, stream>>>(y2, f3, b3p, (void*)out);
    }
}

// Round 6
// 396.908 us; speedup vs baseline: 1.3726x; 1.0188x over previous
//
#include <hip/hip_runtime.h>

// 4D conv net, MI355X. S=30, B=2, ch 1->10->10->1, kernel 3^4, pad 1, ReLU.
// out = net(x,w) + net(x,w_swap), w_swap has (k1,k2)<->(k3,k4).
// R7: all layers as 32x32x16 bf16 MFMA, M = 32 padded t-positions, K = 16
// channels, N = k4*10+co. Cross-k4 combine in epilogue via per-wave LDS.
// R8: XCD-chunk swizzle, full-line stores, barrier-free epilogue.
// R9/R10: depth-1 A/B prefetch + s-outer/r-inner MFMA order.
// R12: launch_bounds(256,2) + uniform straight-line tap body (junk row for
// wave 3) -> 85 -> 72 us/dispatch.
// R13: all six dispatches cost ~72 us regardless of FLOPs -> cost is the
// 9-tap loop STRUCTURE. Layer 0 (cin=1) packs the 9 (k1,k2) taps into the
// K dimension: A[m][k=k12] = x[g(k12)][h',t'], B[k=k12][n] per k3. One tap,
// 12 MFMAs total (was 103), 54 L2-hot scalar loads, no pipeline needed.
// conv0_k replaces conv_k<0>. Layers 1/2 unchanged.

static constexpr int S  = 30;
static constexpr long S4 = 810000;
static constexpr size_t PLANE = 32768;                  // 32*32*16*2 B
static constexpr size_t YBYTES = (size_t)1800 * PLANE;  // [b(2)][g1][g2]

typedef __bf16 bf16x8 __attribute__((ext_vector_type(8)));
typedef float  f32x16 __attribute__((ext_vector_type(16)));
typedef unsigned int  u32;
typedef unsigned short u16;

static __device__ __forceinline__ u16 f2bf(float f) {
    u32 u = __builtin_bit_cast(u32, f);
    return (u16)((u + 0x7fffu + ((u >> 16) & 1u)) >> 16);
}

// ---------------------------------------------------------------------------
// B-fragment tables.
// Main: [set(6)][k12(9)][k3(3)][lane(64)] uint4 (sets 0/1 now unused).
// L0-packed (appended, gid 10368..10751): [branch(2)][k3(3)][lane(64)] uint4,
//   B[k=k12][n=k4*10+co] = w1[co, perm(k1,k2,k3,k4)], k12 = hl*8+j (<9).
__global__ __launch_bounds__(256) void fragprep_k(u32* __restrict__ ft,
    const float* __restrict__ w1, const float* __restrict__ w2,
    const float* __restrict__ w3)
{
    const int gid = blockIdx.x * 256 + threadIdx.x;
    if (gid >= 6 * 27 * 64 + 2 * 3 * 64) return;
    const int lane = gid & 63;
    const int n = lane & 31, hl = lane >> 5;
    u16 us[8];
#pragma unroll
    for (int j = 0; j < 8; ++j) us[j] = 0;

    if (gid < 6 * 27 * 64) {
        int r = gid >> 6;
        const int k3 = r % 3; r /= 3;
        const int k12 = r % 9; const int set = r / 9;
        const int layer = set >> 1, swap = set & 1;
        const int k1 = k12 / 3, k2 = k12 % 3;
        if (n < 30) {
            const int k4 = (n < 10) ? 0 : ((n < 20) ? 1 : 2);
            const int co = n - 10 * k4;
            const int i1 = swap ? k3 : k1, i2 = swap ? k4 : k2;
            const int i3 = swap ? k1 : k3, i4 = swap ? k2 : k4;
            const int widx = ((i1 * 3 + i2) * 3 + i3) * 3 + i4;
#pragma unroll
            for (int j = 0; j < 8; ++j) {
                const int k = hl * 8 + j;
                float wv = 0.f;
                if (layer == 0) { if (k == 0) wv = w1[co * 81 + widx]; }
                else if (layer == 1) { if (k < 10) wv = w2[(co * 10 + k) * 81 + widx]; }
                else { if (k < 10 && co == 0) wv = w3[k * 81 + widx]; }
                us[j] = f2bf(wv);
            }
        }
    } else {
        const int idx = gid - 6 * 27 * 64;       // 0..383
        int r = idx >> 6;                        // 0..5
        const int k3 = r % 3, swap = r / 3;
        if (n < 30) {
            const int k4 = (n < 10) ? 0 : ((n < 20) ? 1 : 2);
            const int co = n - 10 * k4;
#pragma unroll
            for (int j = 0; j < 8; ++j) {
                const int k12 = hl * 8 + j;
                if (k12 < 9) {
                    const int k1 = k12 / 3, k2 = k12 % 3;
                    const int i1 = swap ? k3 : k1, i2 = swap ? k4 : k2;
                    const int i3 = swap ? k1 : k3, i4 = swap ? k2 : k4;
                    const int widx = ((i1 * 3 + i2) * 3 + i3) * 3 + i4;
                    us[j] = f2bf(w1[co * 81 + widx]);
                }
            }
        }
    }
    u32* o = ft + (size_t)gid * 4;
    o[0] = (u32)us[0] | ((u32)us[1] << 16);
    o[1] = (u32)us[2] | ((u32)us[3] << 16);
    o[2] = (u32)us[4] | ((u32)us[5] << 16);
    o[3] = (u32)us[6] | ((u32)us[7] << 16);
}

// ---------------------------------------------------------------------------
// Zero halo positions (h' or t' in {0,31}) of all 1800 planes of y1 and y2.
__global__ __launch_bounds__(128) void zerok(u16* __restrict__ y1, u16* __restrict__ y2)
{
    const int pb = blockIdx.x, tid = threadIdx.x;
    if (tid >= 124) return;
    int hp, tp;
    if (tid < 32)      { hp = 0;        tp = tid; }
    else if (tid < 64) { hp = 31;       tp = tid - 32; }
    else if (tid < 94) { hp = tid - 63; tp = 0; }
    else               { hp = tid - 93; tp = 31; }
    const size_t off = (size_t)pb * PLANE + hp * 1024 + tp * 32;
    const uint4 z = make_uint4(0, 0, 0, 0);
    *(uint4*)((char*)y1 + off)      = z;
    *(uint4*)((char*)y1 + off + 16) = z;
    *(uint4*)((char*)y2 + off)      = z;
    *(uint4*)((char*)y2 + off + 16) = z;
}

// ---------------------------------------------------------------------------
// Layer 0, K-packed: one "tap", 12 MFMAs per wave. Same grid/swizzle/epilogue
// as conv_k. A[m=t'][k=k12] = x[b, g(k12), h'-1, m-1] (0 outside), B per ss.
__global__ __launch_bounds__(256, 4) void conv0_k(
    const float* __restrict__ x, const uint4* __restrict__ bt,
    const float* __restrict__ bias, void* __restrict__ outp)
{
    __shared__ float E[4][1056];
    const int wgid = blockIdx.x + S * blockIdx.y + 900 * blockIdx.z;
    const int id2  = (wgid & 7) * 450 + (wgid >> 3);
    const int half = id2 & 1;
    int sp = id2 >> 1;
    const int w1i = sp % S; sp /= S;
    const int h1  = sp % S;
    const int b   = sp / S;

    const int tid = threadIdx.x;
    const int lane = tid & 63, wv = tid >> 6;
    const int m = lane & 31, hl = lane >> 5;
    const int rbase = half * 15 + wv * 4;

    uint4 Bs[3];
#pragma unroll
    for (int ss = 0; ss < 3; ++ss) Bs[ss] = bt[ss * 64 + lane];

    int gof[9]; int gokm = 0;
#pragma unroll
    for (int k12 = 0; k12 < 9; ++k12) {
        const int g1 = h1 + k12 / 3 - 1, g2 = w1i + k12 % 3 - 1;
        gof[k12] = 0;
        if (g1 >= 0 && g1 < S && g2 >= 0 && g2 < S) {
            gof[k12] = (g1 * S + g2) * 900; gokm |= 1 << k12;
        }
    }
    const float* xb = x + (size_t)b * S4;

    uint4 F[6];
#pragma unroll
    for (int f = 0; f < 6; ++f) {
        const int hp = rbase + f;
        const bool rk = (hp >= 1 && hp <= 30 && m >= 1 && m <= 30);
        const int ro = (hp - 1) * 30 + (m - 1);
        u16 av[8];
#pragma unroll
        for (int j = 0; j < 8; ++j) av[j] = 0;
        if (hl == 0) {
#pragma unroll
            for (int j = 0; j < 8; ++j) {
                float v = 0.f;
                if (rk && ((gokm >> j) & 1)) v = xb[gof[j] + ro];
                av[j] = f2bf(v);
            }
        } else {
            float v = 0.f;
            if (rk && ((gokm >> 8) & 1)) v = xb[gof[8] + ro];
            av[0] = f2bf(v);
        }
        F[f] = make_uint4((u32)av[0] | ((u32)av[1] << 16),
                          (u32)av[2] | ((u32)av[3] << 16),
                          (u32)av[4] | ((u32)av[5] << 16),
                          (u32)av[6] | ((u32)av[7] << 16));
    }

    f32x16 acc[4];
#pragma unroll
    for (int r = 0; r < 4; ++r)
#pragma unroll
        for (int e = 0; e < 16; ++e) acc[r][e] = 0.f;
#pragma unroll
    for (int ss = 0; ss < 3; ++ss)
#pragma unroll
        for (int r = 0; r < 4; ++r)
            acc[r] = __builtin_amdgcn_mfma_f32_32x32x16_bf16(
                __builtin_bit_cast(bf16x8, F[r + ss]),
                __builtin_bit_cast(bf16x8, Bs[ss]), acc[r], 0, 0, 0);

    // epilogue: identical to conv_k LAYER<=1
    float* Ew = E[wv];
    for (int r = 0; r < 4; ++r) {
        if (wv == 3 && r == 3) continue;
#pragma unroll
        for (int gq = 0; gq < 4; ++gq)
#pragma unroll
            for (int r4 = 0; r4 < 4; ++r4)
                Ew[m * 33 + 4 * hl + 8 * gq + r4] = acc[r][gq * 4 + r4];

        const int h2 = rbase + r;
        char* pl = (char*)outp + ((size_t)b * 900 + h1 * S + w1i) * PLANE
                   + (size_t)(h2 + 1) * 1024;
        const int t = lane >> 1, h8 = lane & 1;
        if (t < 30) {
            u32 wo[4];
#pragma unroll
            for (int p = 0; p < 4; ++p) {
                const int c0 = 8 * h8 + 2 * p, c1 = c0 + 1;
                float v0 = 0.f, v1 = 0.f;
                if (c0 < 10)
                    v0 = fmaxf(Ew[c0 * 33 + t] + Ew[(10 + c0) * 33 + t + 1]
                             + Ew[(20 + c0) * 33 + t + 2] + bias[c0], 0.f);
                if (c1 < 10)
                    v1 = fmaxf(Ew[c1 * 33 + t] + Ew[(10 + c1) * 33 + t + 1]
                             + Ew[(20 + c1) * 33 + t + 2] + bias[c1], 0.f);
                wo[p] = (u32)f2bf(v0) | ((u32)f2bf(v1) << 16);
            }
            *(uint4*)(pl + (t + 1) * 32 + h8 * 16) =
                make_uint4(wo[0], wo[1], wo[2], wo[3]);
        }
    }
}

// ---------------------------------------------------------------------------
// Layers 1/2 (unchanged from R12). Wave wv owns rows rbase..rbase+3; wave 3's
// row 3 is junk. Depth-1 A/B prefetch, launch_bounds(256,2).
template<int LAYER, bool ACCUM>
__global__ __launch_bounds__(256, 2) void conv_k(
    const void* __restrict__ inp, const u32* __restrict__ ftab,
    const float* __restrict__ bias, void* __restrict__ outp)
{
    __shared__ float E[4][1056];
    const int wgid = blockIdx.x + S * blockIdx.y + 900 * blockIdx.z;
    const int id2  = (wgid & 7) * 450 + (wgid >> 3);
    const int half = id2 & 1;
    int sp = id2 >> 1;
    const int w1i = sp % S; sp /= S;
    const int h1  = sp % S;
    const int b   = sp / S;

    const int tid = threadIdx.x;
    const int lane = tid & 63, wv = tid >> 6;
    const int m = lane & 31, hl = lane >> 5;
    const int rbase = half * 15 + wv * 4;
    const uint4* ft4 = (const uint4*)ftab;

    int rofs[6];
#pragma unroll
    for (int f = 0; f < 6; ++f) {
        int rr = rbase + f; if (rr > 31) rr = 31;
        rofs[f] = rr * 1024;
    }

    int kl[9], nk = 0;
#pragma unroll
    for (int k12 = 0; k12 < 9; ++k12) {
        const int g1 = h1 + k12 / 3 - 1, g2 = w1i + k12 % 3 - 1;
        if (g1 >= 0 && g1 < S && g2 >= 0 && g2 < S)
            kl[nk++] = (g1 * S + g2) | (k12 << 10);
    }

    f32x16 acc[4];
#pragma unroll
    for (int r = 0; r < 4; ++r)
#pragma unroll
        for (int e = 0; e < 16; ++e) acc[r][e] = 0.f;

    auto loadA = [&](uint4* Fd, int g) {
        const char* P = (const char*)inp + ((size_t)b * 900 + g) * PLANE
                        + m * 32 + hl * 16;
#pragma unroll
        for (int f = 0; f < 6; ++f)
            Fd[f] = *(const uint4*)(P + rofs[f]);
    };

    uint4 B0[3];
    {
        const int k0 = kl[0] >> 10;
#pragma unroll
        for (int f = 0; f < 3; ++f) B0[f] = ft4[(k0 * 3 + f) * 64 + lane];
    }
    uint4 F[6];
    loadA(F, kl[0] & 1023);

    for (int ki = 0; ki + 1 < nk; ++ki) {
        const int gn = kl[ki + 1] & 1023, kn = kl[ki + 1] >> 10;
        uint4 FN[6];
        loadA(FN, gn);
        uint4 BN[3];
#pragma unroll
        for (int f = 0; f < 3; ++f) BN[f] = ft4[(kn * 3 + f) * 64 + lane];

#pragma unroll
        for (int ss = 0; ss < 3; ++ss)
#pragma unroll
            for (int r = 0; r < 4; ++r)
                acc[r] = __builtin_amdgcn_mfma_f32_32x32x16_bf16(
                    __builtin_bit_cast(bf16x8, F[r + ss]),
                    __builtin_bit_cast(bf16x8, B0[ss]), acc[r], 0, 0, 0);

#pragma unroll
        for (int f = 0; f < 6; ++f) F[f] = FN[f];
#pragma unroll
        for (int f = 0; f < 3; ++f) B0[f] = BN[f];
    }
#pragma unroll
    for (int ss = 0; ss < 3; ++ss)
#pragma unroll
        for (int r = 0; r < 4; ++r)
            acc[r] = __builtin_amdgcn_mfma_f32_32x32x16_bf16(
                __builtin_bit_cast(bf16x8, F[r + ss]),
                __builtin_bit_cast(bf16x8, B0[ss]), acc[r], 0, 0, 0);

    float* Ew = E[wv];
    for (int r = 0; r < 4; ++r) {
        if (wv == 3 && r == 3) continue;
#pragma unroll
        for (int gq = 0; gq < 4; ++gq)
#pragma unroll
            for (int r4 = 0; r4 < 4; ++r4)
                Ew[m * 33 + 4 * hl + 8 * gq + r4] = acc[r][gq * 4 + r4];

        const int h2 = rbase + r;
        if (LAYER <= 1) {
            char* pl = (char*)outp + ((size_t)b * 900 + h1 * S + w1i) * PLANE
                       + (size_t)(h2 + 1) * 1024;
            const int t = lane >> 1, h8 = lane & 1;
            if (t < 30) {
                u32 wo[4];
#pragma unroll
                for (int p = 0; p < 4; ++p) {
                    const int c0 = 8 * h8 + 2 * p, c1 = c0 + 1;
                    float v0 = 0.f, v1 = 0.f;
                    if (c0 < 10)
                        v0 = fmaxf(Ew[c0 * 33 + t] + Ew[(10 + c0) * 33 + t + 1]
                                 + Ew[(20 + c0) * 33 + t + 2] + bias[c0], 0.f);
                    if (c1 < 10)
                        v1 = fmaxf(Ew[c1 * 33 + t] + Ew[(10 + c1) * 33 + t + 1]
                                 + Ew[(20 + c1) * 33 + t + 2] + bias[c1], 0.f);
                    wo[p] = (u32)f2bf(v0) | ((u32)f2bf(v1) << 16);
                }
                *(uint4*)(pl + (t + 1) * 32 + h8 * 16) =
                    make_uint4(wo[0], wo[1], wo[2], wo[3]);
            }
        } else {
            if (lane < 30) {
                const int t = lane;
                float v = Ew[t] + Ew[330 + t + 1] + Ew[660 + t + 2] + bias[0];
                v = fmaxf(v, 0.f);
                float* o = (float*)outp + (size_t)b * S4
                           + (size_t)(h1 * S + w1i) * 900 + h2 * 30 + t;
                if (ACCUM) *o += v; else *o = v;
            }
        }
    }
}

// ---------------------------------------------------------------------------
extern "C" void kernel_launch(void* const* d_in, const int* in_sizes, int n_in,
                              void* d_out, int out_size, void* d_ws, size_t ws_size,
                              hipStream_t stream)
{
    const float* x   = (const float*)d_in[0];
    const float* w1p = (const float*)d_in[1];
    const float* b1p = (const float*)d_in[2];
    const float* w2p = (const float*)d_in[3];
    const float* b2p = (const float*)d_in[4];
    const float* w3p = (const float*)d_in[5];
    const float* b3p = (const float*)d_in[6];
    float* out = (float*)d_out;

    // ws: fragtab (6*27*64 + 2*3*64) uint4 = 172032 B | y1 59 MB | y2 59 MB
    u32* ft = (u32*)d_ws;
    const uint4* ftL0 = (const uint4*)d_ws + 6 * 27 * 64;
    u16* y1 = (u16*)((char*)d_ws + 172032);
    u16* y2 = (u16*)((char*)y1 + YBYTES);

    fragprep_k<<<42, 256, 0, stream>>>(ft, w1p, w2p, w3p);
    zerok<<<1800, 128, 0, stream>>>(y1, y2);

    dim3 grid(S, S, 4), blk(256);
    for (int br = 0; br < 2; ++br) {
        const u32* f2 = ft + (size_t)(2 + br) * 27 * 64 * 4;
        const u32* f3 = ft + (size_t)(4 + br) * 27 * 64 * 4;
        conv0_k<<<grid, blk, 0, stream>>>(x, ftL0 + br * 192, b1p, (void*)y1);
        conv_k<1, false><<<grid, blk, 0, stream>>>(y1, f2, b2p, (void*)y2);
        if (br == 0)
            conv_k<2, false><<<grid, blk, 0, stream>>>(y2, f3, b3p, (void*)out);
        else
            conv_k<2, true><<<grid, blk, 0, stream>>>(y2, f3, b3p, (void*)out);
    }
}